// Round 4
// baseline (344.011 us; speedup 1.0000x reference)
//
#include <hip/hip_runtime.h>
#include <math.h>

#define BB 32
#define SS 4096
#define DD 1024

// ---------------------------------------------------------------------------
// Kernel 1: q_proj[b][d] = sum_k query[b][k] * Wa[k][d] + bias[d]
// ---------------------------------------------------------------------------
__global__ __launch_bounds__(64) void qproj_kernel(
    const float* __restrict__ query, const float* __restrict__ Wa,
    const float* __restrict__ bias, float* __restrict__ qproj)
{
    const int tid = threadIdx.x;
    const int d   = blockIdx.x * 64 + tid;
    const int b   = blockIdx.y;

    __shared__ float qlds[DD];
    {
        const float4* qsrc = (const float4*)(query + (size_t)b * DD);
        float4* qdst = (float4*)qlds;
        #pragma unroll
        for (int j = 0; j < 4; ++j) qdst[tid + 64 * j] = qsrc[tid + 64 * j];
    }
    __syncthreads();

    const float* wp = Wa + d;
    float ac0 = 0.f, ac1 = 0.f, ac2 = 0.f, ac3 = 0.f;
    for (int k = 0; k < DD; k += 8) {
        float w0 = wp[(k + 0) * DD], w1 = wp[(k + 1) * DD];
        float w2 = wp[(k + 2) * DD], w3 = wp[(k + 3) * DD];
        float w4 = wp[(k + 4) * DD], w5 = wp[(k + 5) * DD];
        float w6 = wp[(k + 6) * DD], w7 = wp[(k + 7) * DD];
        ac0 += qlds[k + 0] * w0;  ac1 += qlds[k + 1] * w1;
        ac2 += qlds[k + 2] * w2;  ac3 += qlds[k + 3] * w3;
        ac0 += qlds[k + 4] * w4;  ac1 += qlds[k + 5] * w5;
        ac2 += qlds[k + 6] * w6;  ac3 += qlds[k + 7] * w7;
    }
    qproj[(size_t)b * DD + d] = (ac0 + ac1) + (ac2 + ac3) + bias[d];
}

// ---------------------------------------------------------------------------
// Kernel 2: flash partial. 4 waves/block, 2-row batches, 1-batch prefetch.
// Register budget: q(16) + acc(16) + 2 cur rows(32) + 2 next rows(32) ~= 115.
// ---------------------------------------------------------------------------
struct Row { float4 a, b, c, d; };

__device__ __forceinline__ Row load_row(const float4* vp, int lane) {
    Row r;
    r.a = vp[lane]; r.b = vp[64 + lane]; r.c = vp[128 + lane]; r.d = vp[192 + lane];
    return r;
}

__device__ __forceinline__ float dot_row(const Row& r, const Row& q) {
    return r.a.x*q.a.x + r.a.y*q.a.y + r.a.z*q.a.z + r.a.w*q.a.w
         + r.b.x*q.b.x + r.b.y*q.b.y + r.b.z*q.b.z + r.b.w*q.b.w
         + r.c.x*q.c.x + r.c.y*q.c.y + r.c.z*q.c.z + r.c.w*q.c.w
         + r.d.x*q.d.x + r.d.y*q.d.y + r.d.z*q.d.z + r.d.w*q.d.w;
}

__device__ __forceinline__ void process2(
    const Row& r0, const Row& r1, const Row& q,
    float& m, float& l, Row& acc,
    float* scores_w, int batch, int lane)
{
    float s0 = dot_row(r0, q), s1 = dot_row(r1, q);
    #pragma unroll
    for (int off = 32; off; off >>= 1) {
        s0 += __shfl_xor(s0, off, 64);
        s1 += __shfl_xor(s1, off, 64);
    }
    if (lane == 0) *(float2*)(scores_w + batch * 2) = make_float2(s0, s1);

    const float mn = fmaxf(m, fmaxf(s0, s1));
    const float sc = __expf(m - mn);           // m=-inf first -> 0
    const float p0 = __expf(s0 - mn);
    const float p1 = __expf(s1 - mn);
    m = mn;
    l = l * sc + (p0 + p1);
    acc.a.x = acc.a.x*sc + p0*r0.a.x + p1*r1.a.x;
    acc.a.y = acc.a.y*sc + p0*r0.a.y + p1*r1.a.y;
    acc.a.z = acc.a.z*sc + p0*r0.a.z + p1*r1.a.z;
    acc.a.w = acc.a.w*sc + p0*r0.a.w + p1*r1.a.w;
    acc.b.x = acc.b.x*sc + p0*r0.b.x + p1*r1.b.x;
    acc.b.y = acc.b.y*sc + p0*r0.b.y + p1*r1.b.y;
    acc.b.z = acc.b.z*sc + p0*r0.b.z + p1*r1.b.z;
    acc.b.w = acc.b.w*sc + p0*r0.b.w + p1*r1.b.w;
    acc.c.x = acc.c.x*sc + p0*r0.c.x + p1*r1.c.x;
    acc.c.y = acc.c.y*sc + p0*r0.c.y + p1*r1.c.y;
    acc.c.z = acc.c.z*sc + p0*r0.c.z + p1*r1.c.z;
    acc.c.w = acc.c.w*sc + p0*r0.c.w + p1*r1.c.w;
    acc.d.x = acc.d.x*sc + p0*r0.d.x + p1*r1.d.x;
    acc.d.y = acc.d.y*sc + p0*r0.d.y + p1*r1.d.y;
    acc.d.z = acc.d.z*sc + p0*r0.d.z + p1*r1.d.z;
    acc.d.w = acc.d.w*sc + p0*r0.d.w + p1*r1.d.w;
}

template<int NC>
__global__ __launch_bounds__(256, 4) void attn_partial_kernel(
    const float* __restrict__ values, const float* __restrict__ qproj,
    float* __restrict__ scores, float* __restrict__ pm,
    float* __restrict__ pl, float* __restrict__ pctx)
{
    constexpr int CS  = SS / NC;    // rows per block
    constexpr int RPW = CS / 4;     // rows per wave (contiguous)
    constexpr int NB  = RPW / 2;    // 2-row batches (even)

    const int chunk = blockIdx.x;
    const int b     = blockIdx.y;
    const int tid   = threadIdx.x;
    const int lane  = tid & 63;
    const int wave  = tid >> 6;

    const float4* qp = (const float4*)(qproj + (size_t)b * DD);
    Row q;
    q.a = qp[lane]; q.b = qp[64 + lane]; q.c = qp[128 + lane]; q.d = qp[192 + lane];

    float m = -INFINITY, l = 0.f;
    Row acc;
    acc.a = make_float4(0,0,0,0); acc.b = acc.a; acc.c = acc.a; acc.d = acc.a;

    const int row0 = wave * RPW;
    const size_t vbase = ((size_t)b * SS + (size_t)chunk * CS + row0) * DD;
    const float4* vp = (const float4*)(values + vbase);   // row i at vp + i*256
    float* scores_w = scores + (size_t)b * SS + (size_t)chunk * CS + row0;

    // double-buffered 2-row batches: X = cur, Y = next
    Row X0 = load_row(vp + 0 * 256, lane);
    Row X1 = load_row(vp + 1 * 256, lane);
    Row Y0, Y1;

    #pragma unroll 2
    for (int t = 0; t < NB; t += 2) {
        {
            const float4* nvp = vp + (size_t)(t + 1) * 2 * 256;
            Y0 = load_row(nvp + 0 * 256, lane);
            Y1 = load_row(nvp + 1 * 256, lane);
            process2(X0, X1, q, m, l, acc, scores_w, t, lane);
        }
        {
            if (t + 2 < NB) {
                const float4* nvp = vp + (size_t)(t + 2) * 2 * 256;
                X0 = load_row(nvp + 0 * 256, lane);
                X1 = load_row(nvp + 1 * 256, lane);
            }
            process2(Y0, Y1, q, m, l, acc, scores_w, t + 1, lane);
        }
    }

    // ---- block combine of the 4 wave partials ----
    __shared__ float  smx[4], slx[4];
    __shared__ float4 sacc[4][256];
    sacc[wave][lane]       = acc.a;
    sacc[wave][64 + lane]  = acc.b;
    sacc[wave][128 + lane] = acc.c;
    sacc[wave][192 + lane] = acc.d;
    if (lane == 0) { smx[wave] = m; slx[wave] = l; }
    __syncthreads();

    const float mb = fmaxf(fmaxf(smx[0], smx[1]), fmaxf(smx[2], smx[3]));
    const float c0 = __expf(smx[0] - mb), c1 = __expf(smx[1] - mb);
    const float c2 = __expf(smx[2] - mb), c3 = __expf(smx[3] - mb);
    const float lb = c0*slx[0] + c1*slx[1] + c2*slx[2] + c3*slx[3];

    const float4 t0 = sacc[0][tid], t1 = sacc[1][tid], t2 = sacc[2][tid], t3 = sacc[3][tid];
    float4 r;
    r.x = c0*t0.x + c1*t1.x + c2*t2.x + c3*t3.x;
    r.y = c0*t0.y + c1*t1.y + c2*t2.y + c3*t3.y;
    r.z = c0*t0.z + c1*t1.z + c2*t2.z + c3*t3.z;
    r.w = c0*t0.w + c1*t1.w + c2*t2.w + c3*t3.w;
    ((float4*)pctx)[((size_t)b * NC + chunk) * 256 + tid] = r;
    if (tid == 0) {
        pm[b * NC + chunk] = mb;
        pl[b * NC + chunk] = lb;
    }
}

// ---------------------------------------------------------------------------
// Kernel 3: exact recombination across the NC chunk partials.
// ---------------------------------------------------------------------------
template<int NC>
__global__ __launch_bounds__(256) void attn_finalize_kernel(
    const float* __restrict__ pm, const float* __restrict__ pl,
    const float* __restrict__ pctx, const float* __restrict__ scores,
    float* __restrict__ out)
{
    const int b   = blockIdx.x;
    const int tid = threadIdx.x;

    float M = -INFINITY;
    #pragma unroll
    for (int c = 0; c < NC; ++c) M = fmaxf(M, pm[b * NC + c]);

    float L = 0.f;
    #pragma unroll
    for (int c = 0; c < NC; ++c) L += __expf(pm[b * NC + c] - M) * pl[b * NC + c];
    const float invL = 1.0f / L;

    {
        const float4* pc = (const float4*)pctx + (size_t)b * NC * 256;
        float4 acc = make_float4(0,0,0,0);
        #pragma unroll
        for (int c = 0; c < NC; ++c) {
            const float cf = __expf(pm[b * NC + c] - M);
            const float4 t = pc[(size_t)c * 256 + tid];
            acc.x += cf * t.x;  acc.y += cf * t.y;
            acc.z += cf * t.z;  acc.w += cf * t.w;
        }
        float4 r;
        r.x = acc.x * invL; r.y = acc.y * invL; r.z = acc.z * invL; r.w = acc.w * invL;
        ((float4*)out)[(size_t)b * 256 + tid] = r;
    }

    float* wout = out + (size_t)BB * DD;
    const float* sc = scores + (size_t)b * SS;
    for (int s = tid; s < SS; s += 256) {
        wout[(size_t)b * SS + s] = __expf(sc[s] - M) * invL;
    }
}

// ---------------------------------------------------------------------------
// Workspace layout (compile-time per NC), offsets 256B-aligned.
// ---------------------------------------------------------------------------
template<int NC>
struct WsOff {
    static constexpr size_t qproj  = 0;                                   // 131072
    static constexpr size_t scores = qproj + (size_t)BB * DD * 4;         // 524288
    static constexpr size_t pm     = scores + (size_t)BB * SS * 4;
    static constexpr size_t pl     = pm + (((size_t)BB * NC * 4 + 255) & ~255ull);
    static constexpr size_t pctx   = pl + (((size_t)BB * NC * 4 + 255) & ~255ull);
    static constexpr size_t total  = pctx + (size_t)BB * NC * DD * 4;
};

template<int NC>
static void launch_all(const float* query, const float* values, const float* Wa,
                       const float* bias, float* out, char* ws, hipStream_t stream)
{
    float* qproj  = (float*)(ws + WsOff<NC>::qproj);
    float* scores = (float*)(ws + WsOff<NC>::scores);
    float* pm     = (float*)(ws + WsOff<NC>::pm);
    float* pl     = (float*)(ws + WsOff<NC>::pl);
    float* pctx   = (float*)(ws + WsOff<NC>::pctx);

    dim3 g1(DD / 64, BB);
    qproj_kernel<<<g1, 64, 0, stream>>>(query, Wa, bias, qproj);

    dim3 g2(NC, BB);
    attn_partial_kernel<NC><<<g2, 256, 0, stream>>>(values, qproj, scores, pm, pl, pctx);

    attn_finalize_kernel<NC><<<BB, 256, 0, stream>>>(pm, pl, pctx, scores, out);
}

extern "C" void kernel_launch(void* const* d_in, const int* in_sizes, int n_in,
                              void* d_out, int out_size, void* d_ws, size_t ws_size,
                              hipStream_t stream) {
    const float* query  = (const float*)d_in[0];
    const float* values = (const float*)d_in[1];
    const float* Wa     = (const float*)d_in[2];
    const float* bias   = (const float*)d_in[3];
    float* out = (float*)d_out;
    char* ws = (char*)d_ws;

    if (ws_size >= WsOff<32>::total) {
        launch_all<32>(query, values, Wa, bias, out, ws, stream);   // 1024 blocks -> 4 blocks/CU
    } else {
        launch_all<16>(query, values, Wa, bias, out, ws, stream);   // fallback
    }
}

// Round 5
// 147.464 us; speedup vs baseline: 2.3328x; 2.3328x over previous
//
#include <hip/hip_runtime.h>
#include <math.h>

#define BB 32
#define SS 4096
#define DD 1024
#define NC 16                 // chunks: grid = NC x BB = 512 blocks
#define CS (SS / NC)          // 256 rows per block
#define TROWS 8               // rows per LDS tile (32 KB)
#define NT (CS / TROWS)       // 32 tiles per block

// ---------------------------------------------------------------------------
// async global->LDS DMA, 16B per lane. LDS dest is wave-uniform base
// (HW writes lane i at base + i*16); global src is per-lane.
// ---------------------------------------------------------------------------
__device__ __forceinline__ void async_copy16(const float* g, float* l) {
    __builtin_amdgcn_global_load_lds(
        (const __attribute__((address_space(1))) void*)g,
        (__attribute__((address_space(3))) void*)l,
        16, 0, 0);
}

// stage one 32KB tile (TROWS rows = 32 x 1KB chunks); wave w issues chunks
// [w*8, w*8+8) -> exactly 8 outstanding VMEM ops per wave per tile.
__device__ __forceinline__ void stage_tile(const float* gbase, float* lbuf,
                                           int wave, int lane) {
    #pragma unroll
    for (int i = 0; i < 8; ++i) {
        const int c = wave * 8 + i;
        async_copy16(gbase + c * 256 + lane * 4, lbuf + c * 256);
    }
}

// ---------------------------------------------------------------------------
// Kernel 1: q_proj = query @ Wa + bias
// ---------------------------------------------------------------------------
__global__ __launch_bounds__(64) void qproj_kernel(
    const float* __restrict__ query, const float* __restrict__ Wa,
    const float* __restrict__ bias, float* __restrict__ qproj)
{
    const int tid = threadIdx.x;
    const int d   = blockIdx.x * 64 + tid;
    const int b   = blockIdx.y;

    __shared__ float qlds[DD];
    {
        const float4* qsrc = (const float4*)(query + (size_t)b * DD);
        float4* qdst = (float4*)qlds;
        #pragma unroll
        for (int j = 0; j < 4; ++j) qdst[tid + 64 * j] = qsrc[tid + 64 * j];
    }
    __syncthreads();

    const float* wp = Wa + d;
    float ac0 = 0.f, ac1 = 0.f, ac2 = 0.f, ac3 = 0.f;
    for (int k = 0; k < DD; k += 8) {
        float w0 = wp[(k + 0) * DD], w1 = wp[(k + 1) * DD];
        float w2 = wp[(k + 2) * DD], w3 = wp[(k + 3) * DD];
        float w4 = wp[(k + 4) * DD], w5 = wp[(k + 5) * DD];
        float w6 = wp[(k + 6) * DD], w7 = wp[(k + 7) * DD];
        ac0 += qlds[k + 0] * w0;  ac1 += qlds[k + 1] * w1;
        ac2 += qlds[k + 2] * w2;  ac3 += qlds[k + 3] * w3;
        ac0 += qlds[k + 4] * w4;  ac1 += qlds[k + 5] * w5;
        ac2 += qlds[k + 6] * w6;  ac3 += qlds[k + 7] * w7;
    }
    qproj[(size_t)b * DD + d] = (ac0 + ac1) + (ac2 + ac3) + bias[d];
}

// ---------------------------------------------------------------------------
// Kernel 2: flash partial, LDS-DMA double-buffered tiles.
// ---------------------------------------------------------------------------
struct Row { float4 a, b, c, d; };

__device__ __forceinline__ void process2_lds(
    const float* row0, const float* row1, const Row& q,
    float& m, float& l, Row& acc, float* scores_w, int lane)
{
    const float4* r0p = (const float4*)row0;
    const float4* r1p = (const float4*)row1;
    Row r0, r1;
    r0.a = r0p[lane]; r0.b = r0p[64 + lane]; r0.c = r0p[128 + lane]; r0.d = r0p[192 + lane];
    r1.a = r1p[lane]; r1.b = r1p[64 + lane]; r1.c = r1p[128 + lane]; r1.d = r1p[192 + lane];

    float s0 = r0.a.x*q.a.x + r0.a.y*q.a.y + r0.a.z*q.a.z + r0.a.w*q.a.w
             + r0.b.x*q.b.x + r0.b.y*q.b.y + r0.b.z*q.b.z + r0.b.w*q.b.w
             + r0.c.x*q.c.x + r0.c.y*q.c.y + r0.c.z*q.c.z + r0.c.w*q.c.w
             + r0.d.x*q.d.x + r0.d.y*q.d.y + r0.d.z*q.d.z + r0.d.w*q.d.w;
    float s1 = r1.a.x*q.a.x + r1.a.y*q.a.y + r1.a.z*q.a.z + r1.a.w*q.a.w
             + r1.b.x*q.b.x + r1.b.y*q.b.y + r1.b.z*q.b.z + r1.b.w*q.b.w
             + r1.c.x*q.c.x + r1.c.y*q.c.y + r1.c.z*q.c.z + r1.c.w*q.c.w
             + r1.d.x*q.d.x + r1.d.y*q.d.y + r1.d.z*q.d.z + r1.d.w*q.d.w;
    #pragma unroll
    for (int off = 32; off; off >>= 1) {
        s0 += __shfl_xor(s0, off, 64);
        s1 += __shfl_xor(s1, off, 64);
    }
    if (lane == 0) *(float2*)scores_w = make_float2(s0, s1);

    const float mn = fmaxf(m, fmaxf(s0, s1));
    const float sc = __expf(m - mn);          // m=-inf first -> 0
    const float p0 = __expf(s0 - mn);
    const float p1 = __expf(s1 - mn);
    m = mn;
    l = l * sc + (p0 + p1);
    acc.a.x = acc.a.x*sc + p0*r0.a.x + p1*r1.a.x;
    acc.a.y = acc.a.y*sc + p0*r0.a.y + p1*r1.a.y;
    acc.a.z = acc.a.z*sc + p0*r0.a.z + p1*r1.a.z;
    acc.a.w = acc.a.w*sc + p0*r0.a.w + p1*r1.a.w;
    acc.b.x = acc.b.x*sc + p0*r0.b.x + p1*r1.b.x;
    acc.b.y = acc.b.y*sc + p0*r0.b.y + p1*r1.b.y;
    acc.b.z = acc.b.z*sc + p0*r0.b.z + p1*r1.b.z;
    acc.b.w = acc.b.w*sc + p0*r0.b.w + p1*r1.b.w;
    acc.c.x = acc.c.x*sc + p0*r0.c.x + p1*r1.c.x;
    acc.c.y = acc.c.y*sc + p0*r0.c.y + p1*r1.c.y;
    acc.c.z = acc.c.z*sc + p0*r0.c.z + p1*r1.c.z;
    acc.c.w = acc.c.w*sc + p0*r0.c.w + p1*r1.c.w;
    acc.d.x = acc.d.x*sc + p0*r0.d.x + p1*r1.d.x;
    acc.d.y = acc.d.y*sc + p0*r0.d.y + p1*r1.d.y;
    acc.d.z = acc.d.z*sc + p0*r0.d.z + p1*r1.d.z;
    acc.d.w = acc.d.w*sc + p0*r0.d.w + p1*r1.d.w;
}

__global__ __launch_bounds__(256) void attn_partial_kernel(
    const float* __restrict__ values, const float* __restrict__ qproj,
    float* __restrict__ scores, float* __restrict__ pm,
    float* __restrict__ pl, float* __restrict__ pctx)
{
    const int chunk = blockIdx.x;
    const int b     = blockIdx.y;
    const int tid   = threadIdx.x;
    const int lane  = tid & 63;
    const int wave  = tid >> 6;

    // 2 x 32KB staging buffers; combine scratch aliases buffer 0 afterwards.
    __shared__ __align__(16) char smem[2 * TROWS * DD * 4];
    float* buf0 = (float*)smem;
    float* buf1 = (float*)(smem + TROWS * DD * 4);
    __shared__ float smx[4], slx[4];

    const float4* qp = (const float4*)(qproj + (size_t)b * DD);
    Row q;
    q.a = qp[lane]; q.b = qp[64 + lane]; q.c = qp[128 + lane]; q.d = qp[192 + lane];

    float m = -INFINITY, l = 0.f;
    Row acc;
    acc.a = make_float4(0,0,0,0); acc.b = acc.a; acc.c = acc.a; acc.d = acc.a;

    const float* gv = values + ((size_t)b * SS + (size_t)chunk * CS) * DD;
    float* scores_base = scores + (size_t)b * SS + (size_t)chunk * CS;

    stage_tile(gv, buf0, wave, lane);          // prologue: tile 0

    #pragma unroll 2
    for (int t = 0; t < NT; ++t) {
        float* lbuf  = (t & 1) ? buf1 : buf0;
        float* lnext = (t & 1) ? buf0 : buf1;
        if (t + 1 < NT) {
            stage_tile(gv + (size_t)(t + 1) * TROWS * DD, lnext, wave, lane);
            // my 8 tile-t DMAs drained (8 newest = tile t+1 stay in flight);
            // barrier => every wave's tile-t chunks landed.
            asm volatile("s_waitcnt vmcnt(8)\n\ts_barrier" ::: "memory");
        } else {
            asm volatile("s_waitcnt vmcnt(0)\n\ts_barrier" ::: "memory");
        }
        process2_lds(lbuf + (2 * wave) * DD, lbuf + (2 * wave + 1) * DD,
                     q, m, l, acc, scores_base + t * TROWS + 2 * wave, lane);
        // everyone done reading lbuf before next iteration's DMA overwrites it
        asm volatile("s_barrier" ::: "memory");
    }

    // ---- block combine of the 4 wave partials (sacc aliases smem) ----
    float4* sacc = (float4*)smem;              // [4][256]
    sacc[wave * 256 + lane]       = acc.a;
    sacc[wave * 256 + 64 + lane]  = acc.b;
    sacc[wave * 256 + 128 + lane] = acc.c;
    sacc[wave * 256 + 192 + lane] = acc.d;
    if (lane == 0) { smx[wave] = m; slx[wave] = l; }
    __syncthreads();

    const float mb = fmaxf(fmaxf(smx[0], smx[1]), fmaxf(smx[2], smx[3]));
    const float c0 = __expf(smx[0] - mb), c1 = __expf(smx[1] - mb);
    const float c2 = __expf(smx[2] - mb), c3 = __expf(smx[3] - mb);
    const float lb = c0*slx[0] + c1*slx[1] + c2*slx[2] + c3*slx[3];

    const float4 t0 = sacc[0*256 + tid], t1 = sacc[1*256 + tid];
    const float4 t2 = sacc[2*256 + tid], t3 = sacc[3*256 + tid];
    float4 r;
    r.x = c0*t0.x + c1*t1.x + c2*t2.x + c3*t3.x;
    r.y = c0*t0.y + c1*t1.y + c2*t2.y + c3*t3.y;
    r.z = c0*t0.z + c1*t1.z + c2*t2.z + c3*t3.z;
    r.w = c0*t0.w + c1*t1.w + c2*t2.w + c3*t3.w;
    ((float4*)pctx)[((size_t)b * NC + chunk) * 256 + tid] = r;
    if (tid == 0) {
        pm[b * NC + chunk] = mb;
        pl[b * NC + chunk] = lb;
    }
}

// ---------------------------------------------------------------------------
// Kernel 3: exact recombination across the NC chunk partials.
// ---------------------------------------------------------------------------
__global__ __launch_bounds__(256) void attn_finalize_kernel(
    const float* __restrict__ pm, const float* __restrict__ pl,
    const float* __restrict__ pctx, const float* __restrict__ scores,
    float* __restrict__ out)
{
    const int b   = blockIdx.x;
    const int tid = threadIdx.x;

    float M = -INFINITY;
    #pragma unroll
    for (int c = 0; c < NC; ++c) M = fmaxf(M, pm[b * NC + c]);

    float coef[NC];
    float L = 0.f;
    #pragma unroll
    for (int c = 0; c < NC; ++c) {
        coef[c] = __expf(pm[b * NC + c] - M);
        L += coef[c] * pl[b * NC + c];
    }
    const float invL = 1.0f / L;

    {
        const float4* pc = (const float4*)pctx + (size_t)b * NC * 256;
        float4 acc = make_float4(0,0,0,0);
        #pragma unroll
        for (int c = 0; c < NC; ++c) {
            const float4 t = pc[(size_t)c * 256 + tid];
            acc.x += coef[c] * t.x;  acc.y += coef[c] * t.y;
            acc.z += coef[c] * t.z;  acc.w += coef[c] * t.w;
        }
        float4 r;
        r.x = acc.x * invL; r.y = acc.y * invL; r.z = acc.z * invL; r.w = acc.w * invL;
        ((float4*)out)[(size_t)b * 256 + tid] = r;
    }

    float* wout = out + (size_t)BB * DD;
    const float* sc = scores + (size_t)b * SS;
    for (int s = tid; s < SS; s += 256) {
        wout[(size_t)b * SS + s] = __expf(sc[s] - M) * invL;
    }
}

extern "C" void kernel_launch(void* const* d_in, const int* in_sizes, int n_in,
                              void* d_out, int out_size, void* d_ws, size_t ws_size,
                              hipStream_t stream) {
    const float* query  = (const float*)d_in[0];
    const float* values = (const float*)d_in[1];
    const float* Wa     = (const float*)d_in[2];
    const float* bias   = (const float*)d_in[3];
    float* out = (float*)d_out;
    char* ws = (char*)d_ws;

    float* qproj  = (float*)(ws);                 // 131072 B
    float* scores = (float*)(ws + 131072);        // 524288 B
    float* pm     = (float*)(ws + 655360);        // 2048 B
    float* pl     = (float*)(ws + 657408);        // 2048 B
    float* pctx   = (float*)(ws + 659456);        // 2 MiB

    dim3 g1(DD / 64, BB);
    qproj_kernel<<<g1, 64, 0, stream>>>(query, Wa, bias, qproj);

    dim3 g2(NC, BB);
    attn_partial_kernel<<<g2, 256, 0, stream>>>(values, qproj, scores, pm, pl, pctx);

    attn_finalize_kernel<<<BB, 256, 0, stream>>>(pm, pl, pctx, scores, out);
}

// Round 6
// 144.711 us; speedup vs baseline: 2.3772x; 1.0190x over previous
//
#include <hip/hip_runtime.h>
#include <math.h>

#define BB 32
#define SS 4096
#define DD 1024
#define NC 16                 // grid = NC x BB = 512 blocks
#define CS (SS / NC)          // 256 rows per block
#define RPW (CS / 4)          // 64 rows per wave
#define NR 4                  // ring depth (rows of 4KB); 16KB per wave

// ---------------------------------------------------------------------------
// async global->LDS DMA, 16B per lane (wave-uniform LDS base, per-lane src).
// ---------------------------------------------------------------------------
__device__ __forceinline__ void async_copy16(const float* g, float* l) {
    __builtin_amdgcn_global_load_lds(
        (const __attribute__((address_space(1))) void*)g,
        (__attribute__((address_space(3))) void*)l,
        16, 0, 0);
}

// ---------------------------------------------------------------------------
// Kernel 1: q_proj = query @ Wa + bias
// ---------------------------------------------------------------------------
__global__ __launch_bounds__(64) void qproj_kernel(
    const float* __restrict__ query, const float* __restrict__ Wa,
    const float* __restrict__ bias, float* __restrict__ qproj)
{
    const int tid = threadIdx.x;
    const int d   = blockIdx.x * 64 + tid;
    const int b   = blockIdx.y;

    __shared__ float qlds[DD];
    {
        const float4* qsrc = (const float4*)(query + (size_t)b * DD);
        float4* qdst = (float4*)qlds;
        #pragma unroll
        for (int j = 0; j < 4; ++j) qdst[tid + 64 * j] = qsrc[tid + 64 * j];
    }
    __syncthreads();

    const float* wp = Wa + d;
    float ac0 = 0.f, ac1 = 0.f, ac2 = 0.f, ac3 = 0.f;
    for (int k = 0; k < DD; k += 8) {
        float w0 = wp[(k + 0) * DD], w1 = wp[(k + 1) * DD];
        float w2 = wp[(k + 2) * DD], w3 = wp[(k + 3) * DD];
        float w4 = wp[(k + 4) * DD], w5 = wp[(k + 5) * DD];
        float w6 = wp[(k + 6) * DD], w7 = wp[(k + 7) * DD];
        ac0 += qlds[k + 0] * w0;  ac1 += qlds[k + 1] * w1;
        ac2 += qlds[k + 2] * w2;  ac3 += qlds[k + 3] * w3;
        ac0 += qlds[k + 4] * w4;  ac1 += qlds[k + 5] * w5;
        ac2 += qlds[k + 6] * w6;  ac3 += qlds[k + 7] * w7;
    }
    qproj[(size_t)b * DD + d] = (ac0 + ac1) + (ac2 + ac3) + bias[d];
}

// ---------------------------------------------------------------------------
// Kernel 2: flash partial. Per-wave private 4-row LDS ring fed by
// global_load_lds; counted per-wave vmcnt waits; NO barriers in main loop.
// Wave w owns rows {w, w+4, w+8, ...} (interleaved for DRAM page locality).
// Lane k keeps the score of its k-th row in a register (no stores in loop,
// so vmcnt arithmetic stays exact: 4 DMA ops per row in flight).
// ---------------------------------------------------------------------------
struct Row { float4 a, b, c, d; };

__global__ __launch_bounds__(256) void attn_partial_kernel(
    const float* __restrict__ values, const float* __restrict__ qproj,
    float* __restrict__ scores, float* __restrict__ pm,
    float* __restrict__ pl, float* __restrict__ pctx)
{
    const int chunk = blockIdx.x;
    const int b     = blockIdx.y;
    const int tid   = threadIdx.x;
    const int lane  = tid & 63;
    const int wave  = tid >> 6;

    __shared__ __align__(16) float ring[4][NR * DD];   // 4 waves x 16KB = 64KB
    __shared__ float smx[4], slx[4];
    float* wring = ring[wave];

    const float4* qp = (const float4*)(qproj + (size_t)b * DD);
    Row q;
    q.a = qp[lane]; q.b = qp[64 + lane]; q.c = qp[128 + lane]; q.d = qp[192 + lane];

    const float* gv = values + ((size_t)b * SS + (size_t)chunk * CS) * DD;

    // issue DMA for this wave's j-th row (global row = 4*j + wave)
    auto issue = [&](int j) {
        const float* src = gv + (size_t)(4 * j + wave) * DD;
        float* dst = wring + (j & (NR - 1)) * DD;
        #pragma unroll
        for (int c = 0; c < 4; ++c)
            async_copy16(src + c * 256 + lane * 4, dst + c * 256);
    };

    issue(0); issue(1); issue(2);      // prologue: 3 rows in flight

    float m = -INFINITY, l = 0.f, myScore = 0.f;
    Row acc;
    acc.a = make_float4(0,0,0,0); acc.b = acc.a; acc.c = acc.a; acc.d = acc.a;

    #pragma unroll 4
    for (int j = 0; j < RPW; ++j) {
        if (j + 3 < RPW) {
            issue(j + 3);
            // newest 12 (rows j+1..j+3) may stay in flight; row j (and all
            // older ops incl. q loads) must have retired.
            asm volatile("s_waitcnt vmcnt(12)" ::: "memory");
        } else if (j + 3 == RPW) {
            asm volatile("s_waitcnt vmcnt(8)" ::: "memory");
        } else if (j + 2 == RPW) {
            asm volatile("s_waitcnt vmcnt(4)" ::: "memory");
        } else {
            asm volatile("s_waitcnt vmcnt(0)" ::: "memory");
        }

        const float4* vp = (const float4*)(wring + (j & (NR - 1)) * DD);
        const float4 va = vp[lane], vb = vp[64 + lane];
        const float4 vc = vp[128 + lane], vd = vp[192 + lane];

        float s = va.x*q.a.x + va.y*q.a.y + va.z*q.a.z + va.w*q.a.w
                + vb.x*q.b.x + vb.y*q.b.y + vb.z*q.b.z + vb.w*q.b.w
                + vc.x*q.c.x + vc.y*q.c.y + vc.z*q.c.z + vc.w*q.c.w
                + vd.x*q.d.x + vd.y*q.d.y + vd.z*q.d.z + vd.w*q.d.w;
        #pragma unroll
        for (int off = 32; off; off >>= 1) s += __shfl_xor(s, off, 64);

        myScore = (lane == j) ? s : myScore;

        const float mn = fmaxf(m, s);
        const float sc = __expf(m - mn);     // m=-inf first iter -> 0
        const float p  = __expf(s - mn);
        m = mn;
        l = l * sc + p;
        acc.a.x = acc.a.x*sc + p*va.x;  acc.a.y = acc.a.y*sc + p*va.y;
        acc.a.z = acc.a.z*sc + p*va.z;  acc.a.w = acc.a.w*sc + p*va.w;
        acc.b.x = acc.b.x*sc + p*vb.x;  acc.b.y = acc.b.y*sc + p*vb.y;
        acc.b.z = acc.b.z*sc + p*vb.z;  acc.b.w = acc.b.w*sc + p*vb.w;
        acc.c.x = acc.c.x*sc + p*vc.x;  acc.c.y = acc.c.y*sc + p*vc.y;
        acc.c.z = acc.c.z*sc + p*vc.z;  acc.c.w = acc.c.w*sc + p*vc.w;
        acc.d.x = acc.d.x*sc + p*vd.x;  acc.d.y = acc.d.y*sc + p*vd.y;
        acc.d.z = acc.d.z*sc + p*vd.z;  acc.d.w = acc.d.w*sc + p*vd.w;
    }

    // lane k holds score of row 4k+wave: scatter once.
    scores[(size_t)b * SS + (size_t)chunk * CS + 4 * lane + wave] = myScore;

    __syncthreads();                       // all waves done with their rings

    // ---- block combine of the 4 wave partials (sacc aliases the ring) ----
    float4* sacc = (float4*)ring;          // [4][256] float4 = 16KB
    sacc[wave * 256 + lane]       = acc.a;
    sacc[wave * 256 + 64 + lane]  = acc.b;
    sacc[wave * 256 + 128 + lane] = acc.c;
    sacc[wave * 256 + 192 + lane] = acc.d;
    if (lane == 0) { smx[wave] = m; slx[wave] = l; }
    __syncthreads();

    const float mb = fmaxf(fmaxf(smx[0], smx[1]), fmaxf(smx[2], smx[3]));
    const float c0 = __expf(smx[0] - mb), c1 = __expf(smx[1] - mb);
    const float c2 = __expf(smx[2] - mb), c3 = __expf(smx[3] - mb);
    const float lb = c0*slx[0] + c1*slx[1] + c2*slx[2] + c3*slx[3];

    const float4 t0 = sacc[0*256 + tid], t1 = sacc[1*256 + tid];
    const float4 t2 = sacc[2*256 + tid], t3 = sacc[3*256 + tid];
    float4 r;
    r.x = c0*t0.x + c1*t1.x + c2*t2.x + c3*t3.x;
    r.y = c0*t0.y + c1*t1.y + c2*t2.y + c3*t3.y;
    r.z = c0*t0.z + c1*t1.z + c2*t2.z + c3*t3.z;
    r.w = c0*t0.w + c1*t1.w + c2*t2.w + c3*t3.w;
    ((float4*)pctx)[((size_t)b * NC + chunk) * 256 + tid] = r;
    if (tid == 0) {
        pm[b * NC + chunk] = mb;
        pl[b * NC + chunk] = lb;
    }
}

// ---------------------------------------------------------------------------
// Kernel 3: exact recombination across the NC chunk partials.
// ---------------------------------------------------------------------------
__global__ __launch_bounds__(256) void attn_finalize_kernel(
    const float* __restrict__ pm, const float* __restrict__ pl,
    const float* __restrict__ pctx, const float* __restrict__ scores,
    float* __restrict__ out)
{
    const int b   = blockIdx.x;
    const int tid = threadIdx.x;

    float M = -INFINITY;
    #pragma unroll
    for (int c = 0; c < NC; ++c) M = fmaxf(M, pm[b * NC + c]);

    float coef[NC];
    float L = 0.f;
    #pragma unroll
    for (int c = 0; c < NC; ++c) {
        coef[c] = __expf(pm[b * NC + c] - M);
        L += coef[c] * pl[b * NC + c];
    }
    const float invL = 1.0f / L;

    {
        const float4* pc = (const float4*)pctx + (size_t)b * NC * 256;
        float4 acc = make_float4(0,0,0,0);
        #pragma unroll
        for (int c = 0; c < NC; ++c) {
            const float4 t = pc[(size_t)c * 256 + tid];
            acc.x += coef[c] * t.x;  acc.y += coef[c] * t.y;
            acc.z += coef[c] * t.z;  acc.w += coef[c] * t.w;
        }
        float4 r;
        r.x = acc.x * invL; r.y = acc.y * invL; r.z = acc.z * invL; r.w = acc.w * invL;
        ((float4*)out)[(size_t)b * 256 + tid] = r;
    }

    float* wout = out + (size_t)BB * DD;
    const float* sc = scores + (size_t)b * SS;
    for (int s = tid; s < SS; s += 256) {
        wout[(size_t)b * SS + s] = __expf(sc[s] - M) * invL;
    }
}

extern "C" void kernel_launch(void* const* d_in, const int* in_sizes, int n_in,
                              void* d_out, int out_size, void* d_ws, size_t ws_size,
                              hipStream_t stream) {
    const float* query  = (const float*)d_in[0];
    const float* values = (const float*)d_in[1];
    const float* Wa     = (const float*)d_in[2];
    const float* bias   = (const float*)d_in[3];
    float* out = (float*)d_out;
    char* ws = (char*)d_ws;

    float* qproj  = (float*)(ws);                 // 131072 B
    float* scores = (float*)(ws + 131072);        // 524288 B
    float* pm     = (float*)(ws + 655360);        // 2048 B
    float* pl     = (float*)(ws + 657408);        // 2048 B
    float* pctx   = (float*)(ws + 659456);        // 2 MiB

    dim3 g1(DD / 64, BB);
    qproj_kernel<<<g1, 64, 0, stream>>>(query, Wa, bias, qproj);

    dim3 g2(NC, BB);
    attn_partial_kernel<<<g2, 256, 0, stream>>>(values, qproj, scores, pm, pl, pctx);

    attn_finalize_kernel<<<BB, 256, 0, stream>>>(pm, pl, pctx, scores, out);
}

// Round 8
// 96.995 us; speedup vs baseline: 3.5467x; 1.4919x over previous
//
#include <hip/hip_runtime.h>
#include <math.h>

#define BB 32
#define SS 4096
#define DD 1024
#define NC 16                 // grid = NC x BB = 512 blocks for kernel 2
#define CS (SS / NC)          // 256 rows per block
#define NW 8                  // waves per block (512 threads)
#define JROWS (CS / NW)       // 32 rows per wave

// clang vector type: legal operand for __builtin_nontemporal_load
typedef float f4 __attribute__((ext_vector_type(4)));

__device__ __forceinline__ f4 ntload4(const float* p) {
    return __builtin_nontemporal_load((const f4*)p);
}

// ---------------------------------------------------------------------------
// Kernel 1: q_proj = query @ Wa + bias. 256 thr: 64 d-columns x 4 k-slices.
// ---------------------------------------------------------------------------
__global__ __launch_bounds__(256) void qproj_kernel(
    const float* __restrict__ query, const float* __restrict__ Wa,
    const float* __restrict__ bias, float* __restrict__ qproj)
{
    const int tid    = threadIdx.x;
    const int dlocal = tid & 63;
    const int kslice = tid >> 6;          // 0..3
    const int d      = blockIdx.x * 64 + dlocal;
    const int b      = blockIdx.y;

    __shared__ float qlds[DD];
    ((float4*)qlds)[tid] = ((const float4*)(query + (size_t)b * DD))[tid];
    __syncthreads();

    const float* wp = Wa + d;
    const int k0 = kslice * 256;
    float ac0 = 0.f, ac1 = 0.f, ac2 = 0.f, ac3 = 0.f;
    for (int k = k0; k < k0 + 256; k += 8) {
        float w0 = wp[(k + 0) * DD], w1 = wp[(k + 1) * DD];
        float w2 = wp[(k + 2) * DD], w3 = wp[(k + 3) * DD];
        float w4 = wp[(k + 4) * DD], w5 = wp[(k + 5) * DD];
        float w6 = wp[(k + 6) * DD], w7 = wp[(k + 7) * DD];
        ac0 += qlds[k + 0] * w0;  ac1 += qlds[k + 1] * w1;
        ac2 += qlds[k + 2] * w2;  ac3 += qlds[k + 3] * w3;
        ac0 += qlds[k + 4] * w4;  ac1 += qlds[k + 5] * w5;
        ac2 += qlds[k + 6] * w6;  ac3 += qlds[k + 7] * w7;
    }

    __shared__ float part[4][64];
    part[kslice][dlocal] = (ac0 + ac1) + (ac2 + ac3);
    __syncthreads();

    if (tid < 64) {
        const float s = (part[0][tid] + part[1][tid]) + (part[2][tid] + part[3][tid]);
        const int dd = blockIdx.x * 64 + tid;
        qproj[(size_t)b * DD + dd] = s + bias[dd];
    }
}

// ---------------------------------------------------------------------------
// Kernel 2: flash partial. 8 waves x 512 thr, plain nontemporal float4 loads,
// pair-row processing (2 live rows -> no spill), rows interleaved mod 8.
// ---------------------------------------------------------------------------
__global__ __launch_bounds__(512) void attn_partial_kernel(
    const float* __restrict__ values, const float* __restrict__ qproj,
    float* __restrict__ scores, float* __restrict__ pm,
    float* __restrict__ pl, float* __restrict__ pctx)
{
    const int chunk = blockIdx.x;
    const int b     = blockIdx.y;
    const int tid   = threadIdx.x;
    const int lane  = tid & 63;
    const int wave  = tid >> 6;          // 0..7

    const float* qrow = qproj + (size_t)b * DD;
    const f4 qa = *(const f4*)(qrow + 4 * lane);
    const f4 qb = *(const f4*)(qrow + 256 + 4 * lane);
    const f4 qc = *(const f4*)(qrow + 512 + 4 * lane);
    const f4 qd = *(const f4*)(qrow + 768 + 4 * lane);

    float m = -INFINITY, l = 0.f;
    f4 aa = (f4)(0.f), ab = (f4)(0.f), ac = (f4)(0.f), ad = (f4)(0.f);

    const float* gv = values + ((size_t)b * SS + (size_t)chunk * CS) * DD;
    float* scores_base = scores + (size_t)b * SS + (size_t)chunk * CS;

    for (int j = 0; j < JROWS; j += 2) {
        const int row0 = 8 * j + wave;
        const int row1 = row0 + 8;
        const float* vp0 = gv + (size_t)row0 * DD + 4 * lane;
        const float* vp1 = gv + (size_t)row1 * DD + 4 * lane;
        const f4 r0a = ntload4(vp0);        const f4 r1a = ntload4(vp1);
        const f4 r0b = ntload4(vp0 + 256);  const f4 r1b = ntload4(vp1 + 256);
        const f4 r0c = ntload4(vp0 + 512);  const f4 r1c = ntload4(vp1 + 512);
        const f4 r0d = ntload4(vp0 + 768);  const f4 r1d = ntload4(vp1 + 768);

        const f4 d0 = r0a * qa + r0b * qb + r0c * qc + r0d * qd;
        const f4 d1 = r1a * qa + r1b * qb + r1c * qc + r1d * qd;
        float s0 = (d0.x + d0.y) + (d0.z + d0.w);
        float s1 = (d1.x + d1.y) + (d1.z + d1.w);
        #pragma unroll
        for (int off = 32; off; off >>= 1) {
            s0 += __shfl_xor(s0, off, 64);
            s1 += __shfl_xor(s1, off, 64);
        }
        if (lane == 0) {
            scores_base[row0] = s0;
            scores_base[row1] = s1;
        }

        const float mn = fmaxf(m, fmaxf(s0, s1));
        const float sc = __expf(m - mn);     // m=-inf first iter -> 0
        const float p0 = __expf(s0 - mn);
        const float p1 = __expf(s1 - mn);
        m = mn;
        l = l * sc + (p0 + p1);
        aa = aa * sc + p0 * r0a + p1 * r1a;
        ab = ab * sc + p0 * r0b + p1 * r1b;
        ac = ac * sc + p0 * r0c + p1 * r1c;
        ad = ad * sc + p0 * r0d + p1 * r1d;
    }

    // ---- block combine of the 8 wave partials ----
    __shared__ float smx[NW], slx[NW];
    __shared__ f4 sacc[NW][256];     // 32 KB
    sacc[wave][lane]       = aa;
    sacc[wave][64 + lane]  = ab;
    sacc[wave][128 + lane] = ac;
    sacc[wave][192 + lane] = ad;
    if (lane == 0) { smx[wave] = m; slx[wave] = l; }
    __syncthreads();

    if (tid < 256) {
        float mb = smx[0];
        #pragma unroll
        for (int w = 1; w < NW; ++w) mb = fmaxf(mb, smx[w]);
        float cw[NW];
        float lb = 0.f;
        #pragma unroll
        for (int w = 0; w < NW; ++w) {
            cw[w] = __expf(smx[w] - mb);
            lb += cw[w] * slx[w];
        }
        f4 r = (f4)(0.f);
        #pragma unroll
        for (int w = 0; w < NW; ++w) r += cw[w] * sacc[w][tid];
        ((f4*)pctx)[((size_t)b * NC + chunk) * 256 + tid] = r;
        if (tid == 0) {
            pm[b * NC + chunk] = mb;
            pl[b * NC + chunk] = lb;
        }
    }
}

// ---------------------------------------------------------------------------
// Kernel 3: recombination. grid (8, BB): slice 0 also writes context; every
// slice writes weights for its 512-score stripe.
// ---------------------------------------------------------------------------
__global__ __launch_bounds__(256) void attn_finalize_kernel(
    const float* __restrict__ pm, const float* __restrict__ pl,
    const float* __restrict__ pctx, const float* __restrict__ scores,
    float* __restrict__ out)
{
    const int slice = blockIdx.x;        // 0..7
    const int b     = blockIdx.y;
    const int tid   = threadIdx.x;

    float M = -INFINITY;
    #pragma unroll
    for (int c = 0; c < NC; ++c) M = fmaxf(M, pm[b * NC + c]);

    float L = 0.f;
    #pragma unroll
    for (int c = 0; c < NC; ++c) L += __expf(pm[b * NC + c] - M) * pl[b * NC + c];
    const float invL = 1.0f / L;

    if (slice == 0) {
        const f4* pc = (const f4*)pctx + (size_t)b * NC * 256;
        f4 acc = (f4)(0.f);
        #pragma unroll
        for (int c = 0; c < NC; ++c) {
            const float cf = __expf(pm[b * NC + c] - M);
            acc += cf * pc[(size_t)c * 256 + tid];
        }
        ((f4*)out)[(size_t)b * 256 + tid] = acc * invL;
    }

    float* wout = out + (size_t)BB * DD + (size_t)b * SS + slice * 512;
    const float* sc = scores + (size_t)b * SS + slice * 512;
    wout[tid]       = __expf(sc[tid]       - M) * invL;
    wout[tid + 256] = __expf(sc[tid + 256] - M) * invL;
}

extern "C" void kernel_launch(void* const* d_in, const int* in_sizes, int n_in,
                              void* d_out, int out_size, void* d_ws, size_t ws_size,
                              hipStream_t stream) {
    const float* query  = (const float*)d_in[0];
    const float* values = (const float*)d_in[1];
    const float* Wa     = (const float*)d_in[2];
    const float* bias   = (const float*)d_in[3];
    float* out = (float*)d_out;
    char* ws = (char*)d_ws;

    float* qproj  = (float*)(ws);                 // 131072 B
    float* scores = (float*)(ws + 131072);        // 524288 B
    float* pm     = (float*)(ws + 655360);        // 2048 B
    float* pl     = (float*)(ws + 657408);        // 2048 B
    float* pctx   = (float*)(ws + 659456);        // 2 MiB

    dim3 g1(DD / 64, BB);
    qproj_kernel<<<g1, 256, 0, stream>>>(query, Wa, bias, qproj);

    dim3 g2(NC, BB);
    attn_partial_kernel<<<g2, 512, 0, stream>>>(values, qproj, scores, pm, pl, pctx);

    dim3 g3(8, BB);
    attn_finalize_kernel<<<g3, 256, 0, stream>>>(pm, pl, pctx, scores, out);
}